// Round 2
// baseline (38837.119 us; speedup 1.0000x reference)
//
#include <hip/hip_runtime.h>

typedef _Float16 f16;
typedef _Float16 f16x8 __attribute__((ext_vector_type(8)));
typedef _Float16 f16x4 __attribute__((ext_vector_type(4)));
typedef float f32x4 __attribute__((ext_vector_type(4)));

#define T_TOT 2048
#define BATCH 64
#define HID 256
#define G3 768
#define WS 32
#define NWIN 64
#define NRING 4
#define IPT 12288                   // f16 per timestep per lg: 3 gates x 256 j x 16 b
#define IPSLOT (WS * IPT)           // 393216 f16 per ring slot

#define NLOG2E -1.44269504088896f   // -log2(e): sigmoid pre-scale
#define P2LOG2E 2.88539008177793f   // +2*log2(e): tanh pre-scale

#define SPIN_BUDGET 20000000L       // shared per-thread spin budget: bails instead of hanging

// flags (monotone counters: adds or single-writer stores), zero-initialized:
#define F_HCNT(lg,h) ((lg)*2 + (h))            // 0..47   8*(h versions published) [adds only]
#define F_IPC(lg,h)  (48 + (lg)*2 + (h))       // 48..95  scan half: ip windows consumed
#define F_YP(lg,h)   (96 + (lg)*2 + (h))       // 96..143 scan half: y windows produced
#define F_IPP(lg,q)  (144 + (lg)*4 + (q))      // worker q of lg: ip produced
#define F_YC(lg,q)   (240 + (lg)*4 + (q))      // worker q of layer l+1: y consumed

__device__ __forceinline__ float fexp2(float x) { return __builtin_amdgcn_exp2f(x); }
__device__ __forceinline__ float frcp(float x) { return __builtin_amdgcn_rcpf(x); }

__device__ __forceinline__ void st_rel(int* p, int v) {
    __hip_atomic_store(p, v, __ATOMIC_RELEASE, __HIP_MEMORY_SCOPE_AGENT);
}
__device__ __forceinline__ int ld_rlx(int* p) {
    return __hip_atomic_load(p, __ATOMIC_RELAXED, __HIP_MEMORY_SCOPE_AGENT);
}
__device__ __forceinline__ void add_rel(int* p, int v) {
    __hip_atomic_fetch_add(p, v, __ATOMIC_RELEASE, __HIP_MEMORY_SCOPE_AGENT);
}
__device__ __forceinline__ void wait4_ge(int* f, int target, int tid, long& budget) {
    if (tid == 0) {
        #pragma unroll
        for (int q = 0; q < 4; ++q)
            while (ld_rlx(f + q) < target) {
                if (--budget < 0) break;
                __builtin_amdgcn_s_sleep(4);
            }
        __builtin_amdgcn_fence(__ATOMIC_ACQUIRE, "agent");
    }
    __syncthreads();
}
__device__ __forceinline__ void wait2_ge(int* f, int target, int tid, long& budget) {
    if (tid == 0) {
        #pragma unroll
        for (int q = 0; q < 2; ++q)
            while (ld_rlx(f + q) < target) {
                if (--budget < 0) break;
                __builtin_amdgcn_s_sleep(4);
            }
        __builtin_amdgcn_fence(__ATOMIC_ACQUIRE, "agent");
    }
    __syncthreads();
}
// per-wave spin (latency-critical per-step handshake; no block barrier).
// Fast path, then 64 tight retries, then s_sleep(1) retries bounded by budget.
__device__ __forceinline__ void wave_wait_ge(int* f, int target, long& budget) {
    if (ld_rlx(f) < target) {
        int spins = 0;
        while (ld_rlx(f) < target) {
            if (++spins > 64) {
                if (--budget < 0) break;
                __builtin_amdgcn_s_sleep(1);
            }
        }
    }
    __builtin_amdgcn_fence(__ATOMIC_ACQUIRE, "agent");
}
// barrier draining ONLY LDS ops; global loads/stores stay in flight
__device__ __forceinline__ void bar_lgkm() {
    asm volatile("s_waitcnt lgkmcnt(0)\n\ts_barrier" ::: "memory");
}

__global__ void cvt_f16(const float* __restrict__ s, f16* __restrict__ d, int n) {
    int i = (blockIdx.x * 256 + threadIdx.x) * 4;
    if (i + 3 < n) {
        f32x4 v = *(const f32x4*)(s + i);
        f16x4 o = { (f16)v[0], (f16)v[1], (f16)v[2], (f16)v[3] };
        *(f16x4*)(d + i) = o;
    }
}

// W_hh with gate pre-scale: rows<512 (r,z) * -log2e; rows>=512 (n) * 2log2e
__global__ void cvt_whh(const float* __restrict__ s, f16* __restrict__ d, int n) {
    int i = (blockIdx.x * 256 + threadIdx.x) * 4;
    if (i + 3 < n) {
        int row = (i >> 8) % G3;
        float sc = (row < 512) ? NLOG2E : P2LOG2E;
        f32x4 v = *(const f32x4*)(s + i);
        f16x4 o = { (f16)(v[0] * sc), (f16)(v[1] * sc), (f16)(v[2] * sc), (f16)(v[3] * sc) };
        *(f16x4*)(d + i) = o;
    }
}

// biasc[l][g] = scale_g * (b_ih + b_hh for r,z ; b_ih only for n)
__global__ void bias_prep(const float* __restrict__ bi, const float* __restrict__ bh,
                          float* __restrict__ o) {
    int i = blockIdx.x * 256 + threadIdx.x;
    if (i < 6 * G3) {
        int g = i % G3;
        float sc = (g < 512) ? NLOG2E : P2LOG2E;
        o[i] = sc * (bi[i] + (g < 512 ? bh[i] : 0.0f));
    }
}

// bhns[l][j] = 2log2e * b_hh[l][512+j]
__global__ void bhn_prep(const float* __restrict__ bh, float* __restrict__ o) {
    int l = blockIdx.x, j = threadIdx.x;
    o[l * 256 + j] = P2LOG2E * bh[l * G3 + 512 + j];
}

// ---------------- scan role: one block = (layer l, batch group g, HALF hh) -------------
// Each half-block owns h-dims [128*hh, 128*hh+128) for 16 batches; 8 waves, each wave
// computes r/z/n rows for 16 dims (3 MFMA accs x 4 kf own-half + 4 kf peer-half).
// Own half of h(t-1) lives in LDS (FR order: [kgrp 0..15][b 0..15][8] f16); the peer
// half is fetched per step from an L2-resident 2-slot mailbox hx (same FR order),
// published per step via release atomicAdds (8 wave-adds = one version; counter is
// ADD-ONLY so concurrent publishes can never clobber each other).
__device__ void scan_role(const f16* __restrict__ ipring, f16* __restrict__ yring,
                          const f16* __restrict__ whh, const float* __restrict__ bhns,
                          const float* __restrict__ h0, float* __restrict__ out,
                          f16* __restrict__ hx, int* flags, char* smem,
                          int l, int g, int hh, int tid) {
    f16* hb = (f16*)smem;                      // double buffer [2][2048] f16 = 8 KB
    const int wv = tid >> 6, lane = tid & 63;
    const int quad = lane >> 4, b = lane & 15;
    const int dbase = 128 * hh + 16 * wv;      // absolute h-dim base of this wave's rows
    const int lg = l * 4 + g;
    f16* hx_my = hx + (long)(lg * 2 + hh) * 2 * 2048;
    const f16* hx_pe = hx + (long)(lg * 2 + (hh ^ 1)) * 2 * 2048;
    int* hc_my = flags + F_HCNT(lg, hh);
    int* hc_pe = flags + F_HCNT(lg, hh ^ 1);
    long budget = SPIN_BUDGET;

    // A-fragments: rows = gate*256 + dbase + b ; k = kf*32 + quad*8
    f16x8 wf[3][8];
    #pragma unroll
    for (int gate = 0; gate < 3; ++gate) {
        const f16* wp = whh + (long)l * G3 * HID
                      + (gate * 256 + dbase + b) * 256 + quad * 8;
        #pragma unroll
        for (int kf = 0; kf < 8; ++kf)
            wf[gate][kf] = *(const f16x8*)(wp + kf * 32);
    }
    f32x4 bhn = *(const f32x4*)(bhns + l * 256 + dbase + 4 * quad);

    // h0 (own half) -> hb buf0 and hx slot1 (= h(-1)); FR layout
    if (tid < 256) {
        int kgrp = tid >> 4, bb = tid & 15;
        const float* hp = h0 + (long)(l * 64 + g * 16 + bb) * HID + 128 * hh + kgrp * 8;
        f32x4 v0 = *(const f32x4*)hp;
        f32x4 v1 = *(const f32x4*)(hp + 4);
        f16x8 h8 = { (f16)v0[0], (f16)v0[1], (f16)v0[2], (f16)v0[3],
                     (f16)v1[0], (f16)v1[1], (f16)v1[2], (f16)v1[3] };
        *(f16x8*)(&hb[(kgrp * 16 + bb) * 8]) = h8;
        *(f16x8*)(hx_my + 2048 + (kgrp * 16 + bb) * 8) = h8;
    }
    f16x4 hp_;                                  // lane's own 4 h dims, register-resident
    {
        f32x4 v = *(const f32x4*)(h0 + (long)(l * 64 + g * 16 + b) * HID + dbase + 4 * quad);
        hp_ = (f16x4){ (f16)v[0], (f16)v[1], (f16)v[2], (f16)v[3] };
    }
    __syncthreads();                            // each wave drained its vmem before barrier
    if (tid == 0) add_rel(hc_my, 8);            // publish h(-1): ADD (never clobbers step adds)

    // lane addressing constants
    const int lane_off = ((4 * hh + (wv >> 1)) * 4 + quad) * 128 + b * 8 + (wv & 1) * 4;
    const int pfoff = (quad * 16 + b) * 8;      // peer B-fragment base (kk adds 512)
    const int hwoff = ((2 * wv + (quad >> 1)) * 16 + b) * 8 + 4 * (quad & 1);
    const int dimc = dbase + 4 * quad;          // lane's output dims (4)
    const int ko = 4 * hh, kp = 4 * (hh ^ 1);   // own / peer kf bases

    int tstep = 0;
    for (int w = 0; w < NWIN; ++w) {
        if (l < 5 && w >= NRING)
            wait4_ge(flags + F_YC(lg, 0), w - NRING + 1, tid, budget);
        wait4_ge(flags + F_IPP(lg, 0), w + 1, tid, budget);
        const int slot = w & (NRING - 1);
        const f16* ipt = ipring + ((long)lg * NRING + slot) * IPSLOT + lane_off;
        f16* yc = yring + (((long)lg * NRING + slot) * 512 + b) * HID + dimc;
        f16x4 p0 = *(const f16x4*)(ipt);
        f16x4 p1 = *(const f16x4*)(ipt + 4096);
        f16x4 p2 = *(const f16x4*)(ipt + 8192);
        for (int tp = 0; tp < WS; tp += 2) {
            #pragma unroll
            for (int u = 0; u < 2; ++u) {       // slot parity: h(t) -> hx slot u
                // 1) wait peer h(t-1); issue its 4 fragments early (L2, ~1KB/wave)
                wave_wait_ge(hc_pe, 8 * (tstep + 1), budget);
                const f16* ps = hx_pe + (u ^ 1) * 2048 + pfoff;
                f16x8 pf0 = *(const f16x8*)(ps);
                f16x8 pf1 = *(const f16x8*)(ps + 512);
                f16x8 pf2 = *(const f16x8*)(ps + 1024);
                f16x8 pf3 = *(const f16x8*)(ps + 1536);
                // 2) own-half MFMAs hide the peer-load latency
                const int rdo = u * 2048, wro = (u ^ 1) * 2048;
                f32x4 acc[3];
                acc[0] = (f32x4){0.f, 0.f, 0.f, 0.f};
                acc[1] = (f32x4){0.f, 0.f, 0.f, 0.f};
                acc[2] = bhn;                   // pre-scaled b_hh_n in acc init
                #pragma unroll
                for (int kk = 0; kk < 4; ++kk) {
                    f16x8 hf = *(const f16x8*)(&hb[rdo + ((kk * 4 + quad) * 16 + b) * 8]);
                    acc[0] = __builtin_amdgcn_mfma_f32_16x16x32_f16(wf[0][ko + kk], hf, acc[0], 0, 0, 0);
                    acc[1] = __builtin_amdgcn_mfma_f32_16x16x32_f16(wf[1][ko + kk], hf, acc[1], 0, 0, 0);
                    acc[2] = __builtin_amdgcn_mfma_f32_16x16x32_f16(wf[2][ko + kk], hf, acc[2], 0, 0, 0);
                }
                // 3) peer-half MFMAs (compiler inserts fine-grained vmcnt for pf*)
                acc[0] = __builtin_amdgcn_mfma_f32_16x16x32_f16(wf[0][kp + 0], pf0, acc[0], 0, 0, 0);
                acc[1] = __builtin_amdgcn_mfma_f32_16x16x32_f16(wf[1][kp + 0], pf0, acc[1], 0, 0, 0);
                acc[2] = __builtin_amdgcn_mfma_f32_16x16x32_f16(wf[2][kp + 0], pf0, acc[2], 0, 0, 0);
                acc[0] = __builtin_amdgcn_mfma_f32_16x16x32_f16(wf[0][kp + 1], pf1, acc[0], 0, 0, 0);
                acc[1] = __builtin_amdgcn_mfma_f32_16x16x32_f16(wf[1][kp + 1], pf1, acc[1], 0, 0, 0);
                acc[2] = __builtin_amdgcn_mfma_f32_16x16x32_f16(wf[2][kp + 1], pf1, acc[2], 0, 0, 0);
                acc[0] = __builtin_amdgcn_mfma_f32_16x16x32_f16(wf[0][kp + 2], pf2, acc[0], 0, 0, 0);
                acc[1] = __builtin_amdgcn_mfma_f32_16x16x32_f16(wf[1][kp + 2], pf2, acc[1], 0, 0, 0);
                acc[2] = __builtin_amdgcn_mfma_f32_16x16x32_f16(wf[2][kp + 2], pf2, acc[2], 0, 0, 0);
                acc[0] = __builtin_amdgcn_mfma_f32_16x16x32_f16(wf[0][kp + 3], pf3, acc[0], 0, 0, 0);
                acc[1] = __builtin_amdgcn_mfma_f32_16x16x32_f16(wf[1][kp + 3], pf3, acc[1], 0, 0, 0);
                acc[2] = __builtin_amdgcn_mfma_f32_16x16x32_f16(wf[2][kp + 3], pf3, acc[2], 0, 0, 0);
                // 4) activation (4 dims per lane)
                f16x4 hnew;
                #pragma unroll
                for (int r = 0; r < 4; ++r) {
                    float rr = frcp(1.0f + fexp2(acc[0][r] + (float)p0[r]));
                    float zz = frcp(1.0f + fexp2(acc[1][r] + (float)p1[r]));
                    float tt = frcp(1.0f + fexp2((float)p2[r] + rr * acc[2][r]));
                    float nn = 1.0f - 2.0f * tt;
                    hnew[r] = (f16)(nn + zz * ((float)hp_[r] - nn));
                }
                hp_ = hnew;
                // 5) stores: own LDS + peer mailbox, then release-publish (per wave;
                //    release drains this wave's vmem -> peer sees complete fragment)
                *(f16x4*)(&hb[wro + hwoff]) = hnew;
                *(f16x4*)(hx_my + u * 2048 + hwoff) = hnew;
                if (lane == 0) add_rel(hc_my, 1);
                // 6) y store + next-step ip prefetch AFTER publish (kept out of the
                //    release's vmcnt drain); bar_lgkm leaves them in flight
                if (l < 5) *(f16x4*)(yc) = hnew;
                yc += 16 * HID;
                if (tp + u + 1 < WS) ipt += IPT;
                p0 = *(const f16x4*)(ipt);
                p1 = *(const f16x4*)(ipt + 4096);
                p2 = *(const f16x4*)(ipt + 8192);
                bar_lgkm();                     // LDS-only drain, 1 barrier/step
                ++tstep;
            }
        }
        __syncthreads();                        // full drain (vmcnt) before publish
        if (tid == 0) {
            st_rel(flags + F_IPC(lg, hh), w + 1);
            if (l < 5) st_rel(flags + F_YP(lg, hh), w + 1);
        }
    }
    {   // final h (buffer 0 after 2048 steps), own half -> out (f32)
        if (tid < 256) {
            int kgrp = tid >> 4, bb = tid & 15;
            f16x8 h8 = *(const f16x8*)(&hb[(kgrp * 16 + bb) * 8]);
            float* op = out + (long)(l * 64 + g * 16 + bb) * HID + 128 * hh + kgrp * 8;
            f32x4 v0 = { (float)h8[0], (float)h8[1], (float)h8[2], (float)h8[3] };
            f32x4 v1 = { (float)h8[4], (float)h8[5], (float)h8[6], (float)h8[7] };
            *(f32x4*)op = v0;
            *(f32x4*)(op + 4) = v1;
        }
    }
}

// -------- worker role: ip GEMM, 8 waves, one 128-row m-tile (q) per window -------------
// Epilogue: pre-scale and scatter into the lane-fragment ip layout (see scan_role).
// Window row m = t2*16 + b; for fixed (ms,ns): t2 = q*8+2*mi+ms, b = quad*4+r.
template<int K>
__device__ void worker_role(const f16* __restrict__ src, bool is_x, int g,
                            const f16* __restrict__ Wl, const float* __restrict__ bias,
                            f16* __restrict__ dstb, int* flags,
                            int lay, int lg, int plg, int q,
                            char* smem, int tid) {
    f16* As = (f16*)smem;                      // [128][K]
    const int wv = tid >> 6, lane = tid & 63;
    const int quad = lane >> 4, l16 = lane & 15;
    const int mi = wv & 3, ni = wv >> 2;
    constexpr int CPR = K / 8;
    long budget = SPIN_BUDGET;

    for (int w = 0; w < NWIN; ++w) {
        if (lay > 0) wait2_ge(flags + F_YP(plg, 0), w + 1, tid, budget);
        if (w >= NRING) wait2_ge(flags + F_IPC(lg, 0), w - NRING + 1, tid, budget);
        const int slot = w & (NRING - 1);
        f16* dst = dstb + (long)slot * IPSLOT;
        #pragma unroll
        for (int it = 0; it < (128 * CPR) / 512; ++it) {
            int idx = it * 512 + tid;
            int row = idx / CPR, c8 = idx % CPR;
            int wr = q * 128 + row;
            long soff;
            if (is_x) soff = ((long)(w * WS + (wr >> 4)) * 64 + g * 16 + (wr & 15)) * K + c8 * 8;
            else      soff = ((long)slot * 512 + wr) * K + c8 * 8;
            f16x8 v = *(const f16x8*)(src + soff);
            *(f16x8*)(&As[row * K + (c8 ^ (row & 7)) * 8]) = v;
        }
        __syncthreads();
        for (int nt = 0; nt < 6; ++nt) {
            const int cbase = nt * 128 + ni * 64;
            f16x8 bc[4], bn[4];
            #pragma unroll
            for (int ns = 0; ns < 4; ++ns)
                bc[ns] = *(const f16x8*)(Wl + (long)(cbase + ns * 16 + l16) * K + quad * 8);
            f32x4 acc[2][4];
            #pragma unroll
            for (int i = 0; i < 2; ++i)
                #pragma unroll
                for (int j = 0; j < 4; ++j) acc[i][j] = (f32x4){0.f, 0.f, 0.f, 0.f};
            #pragma unroll
            for (int kf = 0; kf < K / 32; ++kf) {
                if (kf + 1 < K / 32) {
                    #pragma unroll
                    for (int ns = 0; ns < 4; ++ns)
                        bn[ns] = *(const f16x8*)(Wl + (long)(cbase + ns * 16 + l16) * K
                                                 + (kf + 1) * 32 + quad * 8);
                }
                f16x8 af[2];
                #pragma unroll
                for (int ms = 0; ms < 2; ++ms) {
                    int row = 32 * mi + 16 * ms + l16;
                    int c8 = (kf * 4 + quad) ^ (row & 7);
                    af[ms] = *(const f16x8*)(&As[row * K + c8 * 8]);
                }
                #pragma unroll
                for (int ms = 0; ms < 2; ++ms)
                    #pragma unroll
                    for (int ns = 0; ns < 4; ++ns)
                        acc[ms][ns] = __builtin_amdgcn_mfma_f32_16x16x32_f16(
                            af[ms], bc[ns], acc[ms][ns], 0, 0, 0);
                #pragma unroll
                for (int ns = 0; ns < 4; ++ns) bc[ns] = bn[ns];
            }
            #pragma unroll
            for (int ns = 0; ns < 4; ++ns) {
                int col = cbase + ns * 16 + l16;
                float bv = bias[col];
                float sc = (col < 512) ? NLOG2E : P2LOG2E;
                // decompose col -> (gate, wv2, s2, quad2, r2) for fragment layout
                int gate = col >> 8, j = col & 255;
                int wv2 = j >> 5, rem = j & 31;
                int s2 = rem >> 4, q2 = (rem & 15) >> 2, r2 = rem & 3;
                #pragma unroll
                for (int ms = 0; ms < 2; ++ms) {
                    int t2 = q * 8 + 2 * mi + ms;
                    f16* dp = dst + t2 * IPT + ((gate * 8 + wv2) * 4 + q2) * 128
                            + s2 * 4 + r2;
                    #pragma unroll
                    for (int r = 0; r < 4; ++r)
                        dp[(quad * 4 + r) * 8] = (f16)(acc[ms][ns][r] * sc + bv);
                }
            }
        }
        __syncthreads();                        // drains ip stores + protects As WAR
        if (tid == 0) {
            st_rel(flags + F_IPP(lg, q), w + 1);
            if (lay > 0) st_rel(flags + F_YC(plg, q), w + 1);
        }
    }
}

// XCD-affine decode: bid = xcd + 8*j, 3 lg per XCD, 6 roles (2 scan halves + 4 workers).
// Scan halves of an lg share the XCD -> hx mailbox + F_HCNT stay in one L2.
__global__ __launch_bounds__(512, 1) void gru_fused(
        const f16* __restrict__ xh, const f16* __restrict__ wih,
        const f16* __restrict__ whh, const float* __restrict__ biasc,
        const float* __restrict__ bhns, const float* __restrict__ h0,
        float* __restrict__ out, f16* __restrict__ yring, f16* __restrict__ ipring,
        f16* __restrict__ hx, int* flags) {
    __shared__ __align__(16) char smem[65536];
    const int bid = blockIdx.x, tid = threadIdx.x;
    const int x = bid & 7, j = bid >> 3;
    const int lgrp = j / 6, role = j % 6;
    const int lg = lgrp * 8 + x;                // 0..23, same-XCD as its peers
    const int l = lg >> 2, g = lg & 3;
    if (role < 2) {
        scan_role(ipring, yring, whh, bhns, h0, out, hx, flags, smem, l, g, role, tid);
    } else {
        const int q = role - 2;
        const float* bias = biasc + l * G3;
        f16* dstb = ipring + (long)lg * NRING * IPSLOT;
        if (l == 0) {
            worker_role<128>(xh, true, g, wih, bias, dstb, flags,
                             0, lg, 0, q, smem, tid);
        } else {
            int plg = (l - 1) * 4 + g;
            const f16* Wl = wih + 768 * 128 + (long)(l - 1) * G3 * HID;
            const f16* src = yring + (long)plg * NRING * 512 * HID;
            worker_role<256>(src, false, g, Wl, bias, dstb, flags,
                             l, lg, plg, q, smem, tid);
        }
    }
}

extern "C" void kernel_launch(void* const* d_in, const int* in_sizes, int n_in,
                              void* d_out, int out_size, void* d_ws, size_t ws_size,
                              hipStream_t stream) {
    const float* x     = (const float*)d_in[0];   // [2048,64,128]
    const float* h0    = (const float*)d_in[1];   // [6,64,256]
    const float* w_ih0 = (const float*)d_in[2];   // [768,128]
    const float* w_ihr = (const float*)d_in[3];   // [5,768,256]
    const float* w_hh  = (const float*)d_in[4];   // [6,768,256]
    const float* b_ih  = (const float*)d_in[5];   // [6,768]
    const float* b_hh  = (const float*)d_in[6];   // [6,768]
    float* out = (float*)d_out;                   // [6,64,256]

    char* p = (char*)d_ws;
    f16* xh      = (f16*)p;   p += (long)T_TOT * BATCH * 128 * 2;        // 33.5 MB
    f16* wih     = (f16*)p;   p += (long)(768 * 128 + 5 * 768 * 256) * 2;
    f16* whh     = (f16*)p;   p += (long)6 * 768 * 256 * 2;
    float* biasc = (float*)p; p += (long)6 * G3 * 4;
    float* bhns  = (float*)p; p += (long)6 * 256 * 4;
    f16* yring   = (f16*)p;   p += (long)20 * NRING * 512 * HID * 2;     // 21 MB
    f16* ipring  = (f16*)p;   p += (long)24 * NRING * IPSLOT * 2;        // 75.5 MB
    f16* hx      = (f16*)p;   p += (long)24 * 2 * 2 * 2048 * 2;          // 384 KB
    int* flags   = (int*)p;   p += 2048;

    hipMemsetAsync(flags, 0, 2048, stream);
    cvt_f16<<<16384, 256, 0, stream>>>(x, xh, T_TOT * BATCH * 128);
    cvt_f16<<<96, 256, 0, stream>>>(w_ih0, wih, 768 * 128);
    cvt_f16<<<960, 256, 0, stream>>>(w_ihr, wih + 768 * 128, 5 * 768 * 256);
    cvt_whh<<<1152, 256, 0, stream>>>(w_hh, whh, 6 * 768 * 256);
    bias_prep<<<18, 256, 0, stream>>>(b_ih, b_hh, biasc);
    bhn_prep<<<6, 256, 0, stream>>>(b_hh, bhns);

    gru_fused<<<144, 512, 0, stream>>>(xh, wih, whh, biasc, bhns, h0, out,
                                       yring, ipring, hx, flags);
}

// Round 3
// 9941.610 us; speedup vs baseline: 3.9065x; 3.9065x over previous
//
#include <hip/hip_runtime.h>

typedef _Float16 f16;
typedef _Float16 f16x8 __attribute__((ext_vector_type(8)));
typedef _Float16 f16x4 __attribute__((ext_vector_type(4)));
typedef float f32x4 __attribute__((ext_vector_type(4)));

#define T_TOT 2048
#define BATCH 64
#define HID 256
#define G3 768
#define WS 32
#define NWIN 64
#define NRING 4
#define IPT 12288                   // f16 per timestep per lg: 3 gates x 256 j x 16 b
#define IPSLOT (WS * IPT)           // 393216 f16 per ring slot

#define NLOG2E -1.44269504088896f   // -log2(e): sigmoid pre-scale
#define P2LOG2E 2.88539008177793f   // +2*log2(e): tanh pre-scale

#define SPIN_BUDGET 20000000L       // bails instead of hanging the queue

// flags (monotone single-writer counters), zero-initialized:
#define F_YPROG(lg)   (lg)                    // scan l: y windows produced
#define F_IPCONS(lg)  (24 + (lg))             // scan l: ip windows consumed
#define F_IPP(lg,q)   (48 + (lg)*4 + (q))     // worker q of layer l: ip produced
#define F_YC(lg,q)    (144 + (lg)*4 + (q))    // worker q of layer l+1: y consumed

__device__ __forceinline__ float fexp2(float x) { return __builtin_amdgcn_exp2f(x); }
__device__ __forceinline__ float frcp(float x) { return __builtin_amdgcn_rcpf(x); }

__device__ __forceinline__ void st_rel(int* p, int v) {
    __hip_atomic_store(p, v, __ATOMIC_RELEASE, __HIP_MEMORY_SCOPE_AGENT);
}
__device__ __forceinline__ int ld_rlx(int* p) {
    return __hip_atomic_load(p, __ATOMIC_RELAXED, __HIP_MEMORY_SCOPE_AGENT);
}
__device__ __forceinline__ void wait_ge(int* f, int target, int tid, long& budget) {
    if (tid == 0) {
        while (ld_rlx(f) < target) {
            if (--budget < 0) break;
            __builtin_amdgcn_s_sleep(4);
        }
        __builtin_amdgcn_fence(__ATOMIC_ACQUIRE, "agent");
    }
    __syncthreads();
}
__device__ __forceinline__ void wait4_ge(int* f, int target, int tid, long& budget) {
    if (tid == 0) {
        #pragma unroll
        for (int q = 0; q < 4; ++q)
            while (ld_rlx(f + q) < target) {
                if (--budget < 0) break;
                __builtin_amdgcn_s_sleep(4);
            }
        __builtin_amdgcn_fence(__ATOMIC_ACQUIRE, "agent");
    }
    __syncthreads();
}
// barrier draining ONLY LDS ops; global loads/stores stay in flight
__device__ __forceinline__ void bar_lgkm() {
    asm volatile("s_waitcnt lgkmcnt(0)\n\ts_barrier" ::: "memory");
}

__global__ void cvt_f16(const float* __restrict__ s, f16* __restrict__ d, int n) {
    int i = (blockIdx.x * 256 + threadIdx.x) * 4;
    if (i + 3 < n) {
        f32x4 v = *(const f32x4*)(s + i);
        f16x4 o = { (f16)v[0], (f16)v[1], (f16)v[2], (f16)v[3] };
        *(f16x4*)(d + i) = o;
    }
}

// W_hh with gate pre-scale: rows<512 (r,z) * -log2e; rows>=512 (n) * 2log2e
__global__ void cvt_whh(const float* __restrict__ s, f16* __restrict__ d, int n) {
    int i = (blockIdx.x * 256 + threadIdx.x) * 4;
    if (i + 3 < n) {
        int row = (i >> 8) % G3;
        float sc = (row < 512) ? NLOG2E : P2LOG2E;
        f32x4 v = *(const f32x4*)(s + i);
        f16x4 o = { (f16)(v[0] * sc), (f16)(v[1] * sc), (f16)(v[2] * sc), (f16)(v[3] * sc) };
        *(f16x4*)(d + i) = o;
    }
}

// biasc[l][g] = scale_g * (b_ih + b_hh for r,z ; b_ih only for n)
__global__ void bias_prep(const float* __restrict__ bi, const float* __restrict__ bh,
                          float* __restrict__ o) {
    int i = blockIdx.x * 256 + threadIdx.x;
    if (i < 6 * G3) {
        int g = i % G3;
        float sc = (g < 512) ? NLOG2E : P2LOG2E;
        o[i] = sc * (bi[i] + (g < 512 ? bh[i] : 0.0f));
    }
}

// bhns[l][j] = 2log2e * b_hh[l][512+j]
__global__ void bhn_prep(const float* __restrict__ bh, float* __restrict__ o) {
    int l = blockIdx.x, j = threadIdx.x;
    o[l * 256 + j] = P2LOG2E * bh[l * G3 + 512 + j];
}

// ---------------- scan role: one block = (layer l, batch group g of 16), 16 waves -----
// Wave wv owns h-dims [16wv,16wv+16): 3 accs (r,z,n) x 8 kf. Weight fragments wf[3][8]
// = 96 VGPRs/wave -> register-resident (the 8-wave version needed 192 and spilled to
// cache reloads). All 8 h fragments are hoisted into hf[8] before the MFMA burst.
// h in LDS in FRAGMENT ORDER: FR(kgrp,b) = (kgrp*16+b)*8 f16, kgrp=dim/8 in [0,32).
__device__ void scan_role(const f16* __restrict__ ipring, f16* __restrict__ yring,
                          const f16* __restrict__ whh, const float* __restrict__ bhns,
                          const float* __restrict__ h0, float* __restrict__ out,
                          int* flags, char* smem, int l, int g, int tid) {
    f16* hb = (f16*)smem;                      // double buffer [2][4096] f16 = 16 KB
    const int wv = tid >> 6, lane = tid & 63;  // wv 0..15
    const int quad = lane >> 4, b = lane & 15;
    const int dbase = 16 * wv;                 // wave's h-dim base
    const int lg = l * 4 + g;
    long budget = SPIN_BUDGET;

    // A-fragments: rows = gate*256 + dbase + b ; k = kf*32 + quad*8
    f16x8 wf[3][8];
    #pragma unroll
    for (int gate = 0; gate < 3; ++gate) {
        const f16* wp = whh + (long)l * G3 * HID
                      + (gate * 256 + dbase + b) * 256 + quad * 8;
        #pragma unroll
        for (int kf = 0; kf < 8; ++kf)
            wf[gate][kf] = *(const f16x8*)(wp + kf * 32);
    }
    f32x4 bhn = *(const f32x4*)(bhns + l * 256 + dbase + 4 * quad);

    // h0 -> buffer 0 in FR layout (512 threads cover 32 kgrp x 16 b)
    if (tid < 512) {
        int kgrp = tid >> 4, bb = tid & 15;
        const float* hp = h0 + (long)(l * 64 + g * 16 + bb) * HID + kgrp * 8;
        f32x4 v0 = *(const f32x4*)hp;
        f32x4 v1 = *(const f32x4*)(hp + 4);
        f16x8 h8 = { (f16)v0[0], (f16)v0[1], (f16)v0[2], (f16)v0[3],
                     (f16)v1[0], (f16)v1[1], (f16)v1[2], (f16)v1[3] };
        *(f16x8*)(&hb[(kgrp * 16 + bb) * 8]) = h8;
    }
    f16x4 hp_;                                  // lane's own 4 h dims, register-resident
    {
        f32x4 v = *(const f32x4*)(h0 + (long)(l * 64 + g * 16 + b) * HID + dbase + 4 * quad);
        hp_ = (f16x4){ (f16)v[0], (f16)v[1], (f16)v[2], (f16)v[3] };
    }
    __syncthreads();

    // lane addressing constants
    // ip element (t,gate,j,b): ((gate*8 + (j>>5))*4 + ((j&15)>>2))*128 + b*8 + ((j>>4)&1)*4 + (j&3)
    // lane needs j = dbase + 4*quad + r -> f16x8 at ((wv>>1)*4+quad)*128 + b*8, sub = 4*(wv&1)
    const int lane_off = ((wv >> 1) * 4 + quad) * 128 + b * 8;
    const int sub = 4 * (wv & 1);
    const int hwoff = ((2 * wv + (quad >> 1)) * 16 + b) * 8 + 4 * (quad & 1);
    const int dimc = dbase + 4 * quad;          // lane's output dims (4)

    for (int w = 0; w < NWIN; ++w) {
        if (l < 5 && w >= NRING)
            wait4_ge(flags + F_YC(lg, 0), w - NRING + 1, tid, budget);
        wait4_ge(flags + F_IPP(lg, 0), w + 1, tid, budget);
        const int slot = w & (NRING - 1);
        const f16* ipt = ipring + ((long)lg * NRING + slot) * IPSLOT + lane_off;
        f16* yc = yring + (((long)lg * NRING + slot) * 512 + b) * HID + dimc;
        f16x8 p0 = *(const f16x8*)(ipt);              // prime t=0: r, z, n blocks
        f16x8 p1 = *(const f16x8*)(ipt + 4096);
        f16x8 p2 = *(const f16x8*)(ipt + 8192);
        for (int tp = 0; tp < WS; tp += 2) {
            #pragma unroll
            for (int u = 0; u < 2; ++u) {
                const int rdo = u * 4096;       // read h(t-1) from buffer u
                const int wro = (u ^ 1) * 4096; // write h(t) to buffer u^1
                // hoist ALL fragment reads (no per-fragment ds_read->MFMA stall)
                f16x8 hf[8];
                #pragma unroll
                for (int kk = 0; kk < 8; ++kk)
                    hf[kk] = *(const f16x8*)(&hb[rdo + ((kk * 4 + quad) * 16 + b) * 8]);
                f32x4 acc0 = (f32x4){0.f, 0.f, 0.f, 0.f};
                f32x4 acc1 = (f32x4){0.f, 0.f, 0.f, 0.f};
                f32x4 acc2 = bhn;               // pre-scaled b_hh_n in acc init
                #pragma unroll
                for (int kk = 0; kk < 8; ++kk) {
                    acc0 = __builtin_amdgcn_mfma_f32_16x16x32_f16(wf[0][kk], hf[kk], acc0, 0, 0, 0);
                    acc1 = __builtin_amdgcn_mfma_f32_16x16x32_f16(wf[1][kk], hf[kk], acc1, 0, 0, 0);
                    acc2 = __builtin_amdgcn_mfma_f32_16x16x32_f16(wf[2][kk], hf[kk], acc2, 0, 0, 0);
                }
                // activation (4 dims per lane)
                f16x4 hnew;
                #pragma unroll
                for (int r = 0; r < 4; ++r) {
                    float rr = frcp(1.0f + fexp2(acc0[r] + (float)p0[sub + r]));
                    float zz = frcp(1.0f + fexp2(acc1[r] + (float)p1[sub + r]));
                    float tt = frcp(1.0f + fexp2((float)p2[sub + r] + rr * acc2[r]));
                    float nn = 1.0f - 2.0f * tt;
                    hnew[r] = (f16)(nn + zz * ((float)hp_[r] - nn));
                }
                hp_ = hnew;
                *(f16x4*)(&hb[wro + hwoff]) = hnew;
                // prefetch t+1 (clamped); loads issue BEFORE y-store (vmcnt FIFO)
                if (tp + u + 1 < WS) ipt += IPT;
                p0 = *(const f16x8*)(ipt);
                p1 = *(const f16x8*)(ipt + 4096);
                p2 = *(const f16x8*)(ipt + 8192);
                if (l < 5) *(f16x4*)(yc) = hnew;
                yc += 16 * HID;
                bar_lgkm();                     // LDS-only drain, 1 barrier/step
            }
        }
        __syncthreads();                        // full drain (vmcnt) before publish
        if (tid == 0) {
            st_rel(flags + F_IPCONS(lg), w + 1);
            if (l < 5) st_rel(flags + F_YPROG(lg), w + 1);
        }
    }
    {   // final h (buffer 0 after 2048 steps) -> out (f32)
        if (tid < 512) {
            int kgrp = tid >> 4, bb = tid & 15;
            f16x8 h8 = *(const f16x8*)(&hb[(kgrp * 16 + bb) * 8]);
            float* op = out + (long)(l * 64 + g * 16 + bb) * HID + kgrp * 8;
            f32x4 v0 = { (float)h8[0], (float)h8[1], (float)h8[2], (float)h8[3] };
            f32x4 v1 = { (float)h8[4], (float)h8[5], (float)h8[6], (float)h8[7] };
            *(f32x4*)op = v0;
            *(f32x4*)(op + 4) = v1;
        }
    }
}

// -------- worker role: ip GEMM, 16 waves, one 128-row m-tile (q) per window -----------
// mi = wv&3 picks the 32-row strip, ni = wv>>2 picks the 64-col strip; nt covers 256
// cols per iteration (3 iterations x 256 = 768). Epilogue: pre-scale and scatter into
// the lane-fragment ip layout (see scan_role). Window row m = t2*16 + b.
template<int K>
__device__ void worker_role(const f16* __restrict__ src, bool is_x, int g,
                            const f16* __restrict__ Wl, const float* __restrict__ bias,
                            f16* __restrict__ dstb, int* flags,
                            int lay, int lg, int plg, int q,
                            char* smem, int tid) {
    f16* As = (f16*)smem;                      // [128][K]
    const int wv = tid >> 6, lane = tid & 63;
    const int quad = lane >> 4, l16 = lane & 15;
    const int mi = wv & 3, ni = wv >> 2;       // mi 0..3, ni 0..3
    constexpr int CPR = K / 8;
    long budget = SPIN_BUDGET;

    for (int w = 0; w < NWIN; ++w) {
        if (lay > 0) wait_ge(flags + F_YPROG(plg), w + 1, tid, budget);
        if (w >= NRING) wait_ge(flags + F_IPCONS(lg), w - NRING + 1, tid, budget);
        const int slot = w & (NRING - 1);
        f16* dst = dstb + (long)slot * IPSLOT;
        #pragma unroll
        for (int it = 0; it < (128 * CPR) / 1024; ++it) {
            int idx = it * 1024 + tid;
            int row = idx / CPR, c8 = idx % CPR;
            int wr = q * 128 + row;
            long soff;
            if (is_x) soff = ((long)(w * WS + (wr >> 4)) * 64 + g * 16 + (wr & 15)) * K + c8 * 8;
            else      soff = ((long)slot * 512 + wr) * K + c8 * 8;
            f16x8 v = *(const f16x8*)(src + soff);
            *(f16x8*)(&As[row * K + (c8 ^ (row & 7)) * 8]) = v;
        }
        __syncthreads();
        for (int nt = 0; nt < 3; ++nt) {
            const int cbase = nt * 256 + ni * 64;
            f16x8 bc[4], bn[4];
            #pragma unroll
            for (int ns = 0; ns < 4; ++ns)
                bc[ns] = *(const f16x8*)(Wl + (long)(cbase + ns * 16 + l16) * K + quad * 8);
            f32x4 acc[2][4];
            #pragma unroll
            for (int i = 0; i < 2; ++i)
                #pragma unroll
                for (int j = 0; j < 4; ++j) acc[i][j] = (f32x4){0.f, 0.f, 0.f, 0.f};
            #pragma unroll
            for (int kf = 0; kf < K / 32; ++kf) {
                if (kf + 1 < K / 32) {
                    #pragma unroll
                    for (int ns = 0; ns < 4; ++ns)
                        bn[ns] = *(const f16x8*)(Wl + (long)(cbase + ns * 16 + l16) * K
                                                 + (kf + 1) * 32 + quad * 8);
                }
                f16x8 af[2];
                #pragma unroll
                for (int ms = 0; ms < 2; ++ms) {
                    int row = 32 * mi + 16 * ms + l16;
                    int c8 = (kf * 4 + quad) ^ (row & 7);
                    af[ms] = *(const f16x8*)(&As[row * K + c8 * 8]);
                }
                #pragma unroll
                for (int ms = 0; ms < 2; ++ms)
                    #pragma unroll
                    for (int ns = 0; ns < 4; ++ns)
                        acc[ms][ns] = __builtin_amdgcn_mfma_f32_16x16x32_f16(
                            af[ms], bc[ns], acc[ms][ns], 0, 0, 0);
                #pragma unroll
                for (int ns = 0; ns < 4; ++ns) bc[ns] = bn[ns];
            }
            #pragma unroll
            for (int ns = 0; ns < 4; ++ns) {
                int col = cbase + ns * 16 + l16;
                float bv = bias[col];
                float sc = (col < 512) ? NLOG2E : P2LOG2E;
                // decompose col -> (gate, wv2, s2, quad2, r2) for fragment layout
                int gate = col >> 8, j = col & 255;
                int wv2 = j >> 5, rem = j & 31;
                int s2 = rem >> 4, q2 = (rem & 15) >> 2, r2 = rem & 3;
                #pragma unroll
                for (int ms = 0; ms < 2; ++ms) {
                    int t2 = q * 8 + 2 * mi + ms;
                    f16* dp = dst + t2 * IPT + ((gate * 8 + wv2) * 4 + q2) * 128
                            + s2 * 4 + r2;
                    #pragma unroll
                    for (int r = 0; r < 4; ++r)
                        dp[(quad * 4 + r) * 8] = (f16)(acc[ms][ns][r] * sc + bv);
                }
            }
        }
        __syncthreads();                        // drains ip stores + protects As WAR
        if (tid == 0) {
            st_rel(flags + F_IPP(lg, q), w + 1);
            if (lay > 0) st_rel(flags + F_YC(plg, q), w + 1);
        }
    }
}

// XCD-affine decode: bid = xcd + 8*j, 3 lg per XCD, 5 roles (1 scan + 4 workers) per lg.
__global__ __launch_bounds__(1024, 1) void gru_fused(
        const f16* __restrict__ xh, const f16* __restrict__ wih,
        const f16* __restrict__ whh, const float* __restrict__ biasc,
        const float* __restrict__ bhns, const float* __restrict__ h0,
        float* __restrict__ out, f16* __restrict__ yring, f16* __restrict__ ipring,
        int* flags) {
    __shared__ __align__(16) char smem[65536];
    const int bid = blockIdx.x, tid = threadIdx.x;
    const int x = bid & 7, j = bid >> 3;
    const int lgrp = j / 5, role = j % 5;
    const int lg = lgrp * 8 + x;                // 0..23, same-XCD as its workers
    const int l = lg >> 2, g = lg & 3;
    if (role == 0) {
        scan_role(ipring, yring, whh, bhns, h0, out, flags, smem, l, g, tid);
    } else {
        const int q = role - 1;
        const float* bias = biasc + l * G3;
        f16* dstb = ipring + (long)lg * NRING * IPSLOT;
        if (l == 0) {
            worker_role<128>(xh, true, g, wih, bias, dstb, flags,
                             0, lg, 0, q, smem, tid);
        } else {
            int plg = (l - 1) * 4 + g;
            const f16* Wl = wih + 768 * 128 + (long)(l - 1) * G3 * HID;
            const f16* src = yring + (long)plg * NRING * 512 * HID;
            worker_role<256>(src, false, g, Wl, bias, dstb, flags,
                             l, lg, plg, q, smem, tid);
        }
    }
}

extern "C" void kernel_launch(void* const* d_in, const int* in_sizes, int n_in,
                              void* d_out, int out_size, void* d_ws, size_t ws_size,
                              hipStream_t stream) {
    const float* x     = (const float*)d_in[0];   // [2048,64,128]
    const float* h0    = (const float*)d_in[1];   // [6,64,256]
    const float* w_ih0 = (const float*)d_in[2];   // [768,128]
    const float* w_ihr = (const float*)d_in[3];   // [5,768,256]
    const float* w_hh  = (const float*)d_in[4];   // [6,768,256]
    const float* b_ih  = (const float*)d_in[5];   // [6,768]
    const float* b_hh  = (const float*)d_in[6];   // [6,768]
    float* out = (float*)d_out;                   // [6,64,256]

    char* p = (char*)d_ws;
    f16* xh      = (f16*)p;   p += (long)T_TOT * BATCH * 128 * 2;        // 33.5 MB
    f16* wih     = (f16*)p;   p += (long)(768 * 128 + 5 * 768 * 256) * 2;
    f16* whh     = (f16*)p;   p += (long)6 * 768 * 256 * 2;
    float* biasc = (float*)p; p += (long)6 * G3 * 4;
    float* bhns  = (float*)p; p += (long)6 * 256 * 4;
    f16* yring   = (f16*)p;   p += (long)20 * NRING * 512 * HID * 2;     // 21 MB
    f16* ipring  = (f16*)p;   p += (long)24 * NRING * IPSLOT * 2;        // 75.5 MB
    int* flags   = (int*)p;   p += 1024;

    hipMemsetAsync(flags, 0, 1024, stream);
    cvt_f16<<<16384, 256, 0, stream>>>(x, xh, T_TOT * BATCH * 128);
    cvt_f16<<<96, 256, 0, stream>>>(w_ih0, wih, 768 * 128);
    cvt_f16<<<960, 256, 0, stream>>>(w_ihr, wih + 768 * 128, 5 * 768 * 256);
    cvt_whh<<<1152, 256, 0, stream>>>(w_hh, whh, 6 * 768 * 256);
    bias_prep<<<18, 256, 0, stream>>>(b_ih, b_hh, biasc);
    bhn_prep<<<6, 256, 0, stream>>>(b_hh, bhns);

    gru_fused<<<120, 1024, 0, stream>>>(xh, wih, whh, biasc, bhns, h0, out,
                                        yring, ipring, flags);
}

// Round 5
// 4795.929 us; speedup vs baseline: 8.0979x; 2.0729x over previous
//
#include <hip/hip_runtime.h>

typedef _Float16 f16;
typedef _Float16 f16x8 __attribute__((ext_vector_type(8)));
typedef _Float16 f16x4 __attribute__((ext_vector_type(4)));
typedef float f32x4 __attribute__((ext_vector_type(4)));

#define T_TOT 2048
#define BATCH 64
#define HID 256
#define G3 768
#define WS 32
#define NWIN 64
#define NRING 4
#define IPT 12288                   // f16 per timestep per lg: 3 gates x 256 j x 16 b
#define IPSLOT (WS * IPT)           // 393216 f16 per ring slot

#define NLOG2E -1.44269504088896f   // -log2(e): sigmoid pre-scale
#define P2LOG2E 2.88539008177793f   // +2*log2(e): tanh pre-scale

#define SPIN_BUDGET 20000000L       // bails instead of hanging the queue

// LDS map (64 KB total — the known-good size on this harness):
//   [0, 48K)  scan: weight slab for kf=7  /  worker: As tile (uses [0,64K))
//   [48K,64K) scan: h double buffer
#define WLDS_BYTES 49152
#define SMEM_BYTES 65536

// flags (monotone single-writer counters), zero-initialized:
#define F_YPROG(lg)   (lg)                    // scan l: y windows produced
#define F_IPCONS(lg)  (24 + (lg))             // scan l: ip windows consumed
#define F_IPP(lg,q)   (48 + (lg)*4 + (q))     // worker q of layer l: ip produced
#define F_YC(lg,q)    (144 + (lg)*4 + (q))    // worker q of layer l+1: y consumed

__device__ __forceinline__ float fexp2(float x) { return __builtin_amdgcn_exp2f(x); }
__device__ __forceinline__ float frcp(float x) { return __builtin_amdgcn_rcpf(x); }

// opaque identity: makes a loaded value NON-rematerializable so the register
// allocator must keep it resident instead of re-loading from memory each use
__device__ __forceinline__ f16x8 opaque(f16x8 v) {
    f32x4 t = __builtin_bit_cast(f32x4, v);
    asm volatile("" : "+v"(t));
    return __builtin_bit_cast(f16x8, t);
}

__device__ __forceinline__ void st_rel(int* p, int v) {
    __hip_atomic_store(p, v, __ATOMIC_RELEASE, __HIP_MEMORY_SCOPE_AGENT);
}
__device__ __forceinline__ int ld_rlx(int* p) {
    return __hip_atomic_load(p, __ATOMIC_RELAXED, __HIP_MEMORY_SCOPE_AGENT);
}
__device__ __forceinline__ void wait_ge(int* f, int target, int tid, long& budget) {
    if (tid == 0) {
        while (ld_rlx(f) < target) {
            if (--budget < 0) break;
            __builtin_amdgcn_s_sleep(4);
        }
        __builtin_amdgcn_fence(__ATOMIC_ACQUIRE, "agent");
    }
    __syncthreads();
}
__device__ __forceinline__ void wait4_ge(int* f, int target, int tid, long& budget) {
    if (tid == 0) {
        #pragma unroll
        for (int q = 0; q < 4; ++q)
            while (ld_rlx(f + q) < target) {
                if (--budget < 0) break;
                __builtin_amdgcn_s_sleep(4);
            }
        __builtin_amdgcn_fence(__ATOMIC_ACQUIRE, "agent");
    }
    __syncthreads();
}
// barrier draining ONLY LDS ops; global loads/stores stay in flight
__device__ __forceinline__ void bar_lgkm() {
    asm volatile("s_waitcnt lgkmcnt(0)\n\ts_barrier" ::: "memory");
}

__global__ void cvt_f16(const float* __restrict__ s, f16* __restrict__ d, int n) {
    int i = (blockIdx.x * 256 + threadIdx.x) * 4;
    if (i + 3 < n) {
        f32x4 v = *(const f32x4*)(s + i);
        f16x4 o = { (f16)v[0], (f16)v[1], (f16)v[2], (f16)v[3] };
        *(f16x4*)(d + i) = o;
    }
}

// W_hh with gate pre-scale: rows<512 (r,z) * -log2e; rows>=512 (n) * 2log2e
__global__ void cvt_whh(const float* __restrict__ s, f16* __restrict__ d, int n) {
    int i = (blockIdx.x * 256 + threadIdx.x) * 4;
    if (i + 3 < n) {
        int row = (i >> 8) % G3;
        float sc = (row < 512) ? NLOG2E : P2LOG2E;
        f32x4 v = *(const f32x4*)(s + i);
        f16x4 o = { (f16)(v[0] * sc), (f16)(v[1] * sc), (f16)(v[2] * sc), (f16)(v[3] * sc) };
        *(f16x4*)(d + i) = o;
    }
}

// biasc[l][g] = scale_g * (b_ih + b_hh for r,z ; b_ih only for n)
__global__ void bias_prep(const float* __restrict__ bi, const float* __restrict__ bh,
                          float* __restrict__ o) {
    int i = blockIdx.x * 256 + threadIdx.x;
    if (i < 6 * G3) {
        int g = i % G3;
        float sc = (g < 512) ? NLOG2E : P2LOG2E;
        o[i] = sc * (bi[i] + (g < 512 ? bh[i] : 0.0f));
    }
}

// bhns[l][j] = 2log2e * b_hh[l][512+j]
__global__ void bhn_prep(const float* __restrict__ bh, float* __restrict__ o) {
    int l = blockIdx.x, j = threadIdx.x;
    o[l * 256 + j] = P2LOG2E * bh[l * G3 + 512 + j];
}

// ---------------- scan role: one block = (layer l, batch group g of 16), 8 waves -------
// Weight residency split (the bottleneck of rounds 0-3 was per-step W_hh re-fetch
// through the CU's L2 port, ~6000 cy/step):
//   kf 0..6 -> REGISTERS: wf[6][7] = 42 frags x 4 VGPR = 168 VGPR/wave (336 KB/CU),
//              each pinned via opaque() so the allocator cannot rematerialize the load.
//   kf 7    -> LDS slab: 8 wv x 6 i x 1 KB = 48 KB/CU, loaded ONCE.
// amdgpu_waves_per_eu(2,2) pins the 256-VGPR budget.
// h in LDS in FRAGMENT ORDER: FR(k,b) = (k*16+b)*8 f16.
// ip in LANE-FRAGMENT ORDER: ip2[t][gate][wv][quad][b][8] -> each lane reads one f16x8.
__device__ void scan_role(const f16* __restrict__ ipring, f16* __restrict__ yring,
                          const f16* __restrict__ whh, const float* __restrict__ bhns,
                          const float* __restrict__ h0, float* __restrict__ out,
                          int* flags, char* smem, int l, int g, int tid) {
    f16* wlds = (f16*)smem;                    // [48 KB) weight slab kf=7
    f16* hb = (f16*)(smem + WLDS_BYTES);       // h double buffer [2][4096] f16 = 16 KB
    const int wv = tid >> 6, lane = tid & 63;
    const int quad = lane >> 4, b = lane & 15;
    const int gbase = 32 * wv + quad * 4;
    const int lg = l * 4 + g;
    const int kk0 = 4 * wv + (quad >> 1);      // gate-write chunk base (s adds 2)
    const int wsub = (quad & 1) * 4;           // 8B sub-offset inside chunk
    long budget = SPIN_BUDGET;

    // A-fragments: rows = (i>>1)*256 + 32wv + (i&1)*16 + b ; k = kf*32 + quad*8
    f16x8 wf[6][7];
    #pragma unroll
    for (int i = 0; i < 6; ++i) {
        const f16* wp = whh + (long)l * G3 * HID
                      + ((i >> 1) * 256 + 32 * wv + (i & 1) * 16 + b) * 256 + quad * 8;
        #pragma unroll
        for (int kf = 0; kf < 7; ++kf)
            wf[i][kf] = opaque(*(const f16x8*)(wp + kf * 32));
        {   // kf 7 -> LDS slab (1 KB per (wv,i) fragment)
            f16x8 v = *(const f16x8*)(wp + 7 * 32);
            *(f16x8*)(&wlds[((wv * 6 + i) * 64 + lane) * 8]) = v;
        }
    }
    f32x4 bhn[2];
    bhn[0] = *(const f32x4*)(bhns + l * 256 + gbase);
    bhn[1] = *(const f32x4*)(bhns + l * 256 + gbase + 16);

    {   // h0 -> buffer 0 in FR layout
        int k = tid >> 4, bb = tid & 15;
        const float* hp = h0 + (long)(l * 64 + g * 16 + bb) * HID + k * 8;
        f32x4 v0 = *(const f32x4*)hp;
        f32x4 v1 = *(const f32x4*)(hp + 4);
        f16x8 h8 = { (f16)v0[0], (f16)v0[1], (f16)v0[2], (f16)v0[3],
                     (f16)v1[0], (f16)v1[1], (f16)v1[2], (f16)v1[3] };
        *(f16x8*)(&hb[(k * 16 + bb) * 8]) = h8;
    }
    f16x4 hp_[2];                               // lane's own h slice, register-resident
    #pragma unroll
    for (int s = 0; s < 2; ++s) {
        f32x4 v = *(const f32x4*)(h0 + (long)(l * 64 + g * 16 + b) * HID + gbase + s * 16);
        hp_[s] = (f16x4){ (f16)v[0], (f16)v[1], (f16)v[2], (f16)v[3] };
    }
    __syncthreads();                            // drains wlds + h0 ds_writes

    const int lane_off = (wv * 4 + quad) * 128 + b * 8;   // lane's slot inside a gate blk
    for (int w = 0; w < NWIN; ++w) {
        if (l < 5 && w >= NRING)
            wait4_ge(flags + F_YC(lg, 0), w - NRING + 1, tid, budget);
        wait4_ge(flags + F_IPP(lg, 0), w + 1, tid, budget);
        const int slot = w & (NRING - 1);
        const f16* ipt = ipring + (long)(lg * NRING + slot) * IPSLOT + lane_off;
        f16* yc = yring + (((long)lg * NRING + slot) * 512 + b) * HID + gbase;
        f16x8 p0 = *(const f16x8*)(ipt);              // prime t=0: r, z, n chunks
        f16x8 p1 = *(const f16x8*)(ipt + 4096);
        f16x8 p2 = *(const f16x8*)(ipt + 8192);
        for (int tp = 0; tp < WS; tp += 2) {
            #pragma unroll
            for (int u = 0; u < 2; ++u) {
                const int rdo = u * 4096;       // read h(t-1) from buffer u
                const int wro = (u ^ 1) * 4096; // write h(t) to buffer u^1
                f32x4 acc[6];
                acc[0] = acc[1] = acc[2] = acc[3] = (f32x4){0.f, 0.f, 0.f, 0.f};
                acc[4] = bhn[0];                // pre-scaled b_hh_n in acc init
                acc[5] = bhn[1];
                #pragma unroll
                for (int kf = 0; kf < 7; ++kf) {   // register-resident weights
                    f16x8 hf = *(const f16x8*)(&hb[rdo + ((kf * 4 + quad) * 16 + b) * 8]);
                    #pragma unroll
                    for (int i = 0; i < 6; ++i)
                        acc[i] = __builtin_amdgcn_mfma_f32_16x16x32_f16(
                            wf[i][kf], hf, acc[i], 0, 0, 0);
                }
                {   // kf 7: LDS-resident weights
                    f16x8 hf = *(const f16x8*)(&hb[rdo + ((7 * 4 + quad) * 16 + b) * 8]);
                    #pragma unroll
                    for (int i = 0; i < 6; ++i) {
                        f16x8 wl = *(const f16x8*)(&wlds[((wv * 6 + i) * 64 + lane) * 8]);
                        acc[i] = __builtin_amdgcn_mfma_f32_16x16x32_f16(
                            wl, hf, acc[i], 0, 0, 0);
                    }
                }
                f16x4 hnew[2];
                #pragma unroll
                for (int s = 0; s < 2; ++s) {
                    #pragma unroll
                    for (int r = 0; r < 4; ++r) {
                        float rr = frcp(1.0f + fexp2(acc[s][r] + (float)p0[s * 4 + r]));
                        float zz = frcp(1.0f + fexp2(acc[2 + s][r] + (float)p1[s * 4 + r]));
                        float tt = frcp(1.0f + fexp2((float)p2[s * 4 + r] + rr * acc[4 + s][r]));
                        float nn = 1.0f - 2.0f * tt;
                        hnew[s][r] = (f16)(nn + zz * ((float)hp_[s][r] - nn));
                    }
                    hp_[s] = hnew[s];
                    *(f16x4*)(&hb[wro + ((kk0 + 2 * s) * 16 + b) * 8 + wsub]) = hnew[s];
                }
                // prefetch t+1 (clamped); loads issue BEFORE y-store (vmcnt FIFO)
                if (tp + u + 1 < WS) ipt += IPT;
                p0 = *(const f16x8*)(ipt);
                p1 = *(const f16x8*)(ipt + 4096);
                p2 = *(const f16x8*)(ipt + 8192);
                if (l < 5) {
                    *(f16x4*)(yc) = hnew[0];
                    *(f16x4*)(yc + 16) = hnew[1];
                }
                yc += 16 * HID;
                bar_lgkm();                     // LDS-only drain, 1 barrier/step
            }
        }
        __syncthreads();                        // full drain (vmcnt) before publish
        if (tid == 0) {
            st_rel(flags + F_IPCONS(lg), w + 1);
            if (l < 5) st_rel(flags + F_YPROG(lg), w + 1);
        }
    }
    {   // final h (buffer 0 after 2048 steps) -> out (f32)
        int k = tid >> 4, bb = tid & 15;
        f16x8 h8 = *(const f16x8*)(&hb[(k * 16 + bb) * 8]);
        float* op = out + (long)(l * 64 + g * 16 + bb) * HID + k * 8;
        f32x4 v0 = { (float)h8[0], (float)h8[1], (float)h8[2], (float)h8[3] };
        f32x4 v1 = { (float)h8[4], (float)h8[5], (float)h8[6], (float)h8[7] };
        *(f32x4*)op = v0;
        *(f32x4*)(op + 4) = v1;
    }
}

// -------- worker role: ip GEMM, 8 waves, one 128-row m-tile (q) per window -------------
// Epilogue: pre-scale and scatter into the lane-fragment ip layout (see scan_role).
// Window row m = t2*16 + b; for fixed (ms,ns): t2 = q*8+2*mi+ms, b = quad*4+r.
template<int K>
__device__ void worker_role(const f16* __restrict__ src, bool is_x, int g,
                            const f16* __restrict__ Wl, const float* __restrict__ bias,
                            f16* __restrict__ dstb, int* flags,
                            int lay, int lg, int plg, int q,
                            char* smem, int tid) {
    f16* As = (f16*)smem;                      // [128][K]
    const int wv = tid >> 6, lane = tid & 63;
    const int quad = lane >> 4, l16 = lane & 15;
    const int mi = wv & 3, ni = wv >> 2;
    constexpr int CPR = K / 8;
    long budget = SPIN_BUDGET;

    for (int w = 0; w < NWIN; ++w) {
        if (lay > 0) wait_ge(flags + F_YPROG(plg), w + 1, tid, budget);
        if (w >= NRING) wait_ge(flags + F_IPCONS(lg), w - NRING + 1, tid, budget);
        const int slot = w & (NRING - 1);
        f16* dst = dstb + (long)slot * IPSLOT;
        #pragma unroll
        for (int it = 0; it < (128 * CPR) / 512; ++it) {
            int idx = it * 512 + tid;
            int row = idx / CPR, c8 = idx % CPR;
            int wr = q * 128 + row;
            long soff;
            if (is_x) soff = ((long)(w * WS + (wr >> 4)) * 64 + g * 16 + (wr & 15)) * K + c8 * 8;
            else      soff = ((long)slot * 512 + wr) * K + c8 * 8;
            f16x8 v = *(const f16x8*)(src + soff);
            *(f16x8*)(&As[row * K + (c8 ^ (row & 7)) * 8]) = v;
        }
        __syncthreads();
        for (int nt = 0; nt < 6; ++nt) {
            const int cbase = nt * 128 + ni * 64;
            f16x8 bc[4], bn[4];
            #pragma unroll
            for (int ns = 0; ns < 4; ++ns)
                bc[ns] = *(const f16x8*)(Wl + (long)(cbase + ns * 16 + l16) * K + quad * 8);
            f32x4 acc[2][4];
            #pragma unroll
            for (int i = 0; i < 2; ++i)
                #pragma unroll
                for (int j = 0; j < 4; ++j) acc[i][j] = (f32x4){0.f, 0.f, 0.f, 0.f};
            #pragma unroll
            for (int kf = 0; kf < K / 32; ++kf) {
                if (kf + 1 < K / 32) {
                    #pragma unroll
                    for (int ns = 0; ns < 4; ++ns)
                        bn[ns] = *(const f16x8*)(Wl + (long)(cbase + ns * 16 + l16) * K
                                                 + (kf + 1) * 32 + quad * 8);
                }
                f16x8 af[2];
                #pragma unroll
                for (int ms = 0; ms < 2; ++ms) {
                    int row = 32 * mi + 16 * ms + l16;
                    int c8 = (kf * 4 + quad) ^ (row & 7);
                    af[ms] = *(const f16x8*)(&As[row * K + c8 * 8]);
                }
                #pragma unroll
                for (int ms = 0; ms < 2; ++ms)
                    #pragma unroll
                    for (int ns = 0; ns < 4; ++ns)
                        acc[ms][ns] = __builtin_amdgcn_mfma_f32_16x16x32_f16(
                            af[ms], bc[ns], acc[ms][ns], 0, 0, 0);
                #pragma unroll
                for (int ns = 0; ns < 4; ++ns) bc[ns] = bn[ns];
            }
            #pragma unroll
            for (int ns = 0; ns < 4; ++ns) {
                int col = cbase + ns * 16 + l16;
                float bv = bias[col];
                float sc = (col < 512) ? NLOG2E : P2LOG2E;
                // decompose col -> (gate, wv2, s2, quad2, r2) for fragment layout
                int gate = col >> 8, j = col & 255;
                int wv2 = j >> 5, rem = j & 31;
                int s2 = rem >> 4, q2 = (rem & 15) >> 2, r2 = rem & 3;
                #pragma unroll
                for (int ms = 0; ms < 2; ++ms) {
                    int t2 = q * 8 + 2 * mi + ms;
                    f16* dp = dst + t2 * IPT + ((gate * 8 + wv2) * 4 + q2) * 128
                            + s2 * 4 + r2;
                    #pragma unroll
                    for (int r = 0; r < 4; ++r)
                        dp[(quad * 4 + r) * 8] = (f16)(acc[ms][ns][r] * sc + bv);
                }
            }
        }
        __syncthreads();                        // drains ip stores + protects As WAR
        if (tid == 0) {
            st_rel(flags + F_IPP(lg, q), w + 1);
            if (lay > 0) st_rel(flags + F_YC(plg, q), w + 1);
        }
    }
}

// XCD-affine decode: bid = xcd + 8*j, 3 lg per XCD, 5 roles (1 scan + 4 workers) per lg.
// waves_per_eu(2,2): pin 2 waves/SIMD -> 256-VGPR budget so scan weights stay resident.
__global__ __launch_bounds__(512) __attribute__((amdgpu_waves_per_eu(2, 2)))
void gru_fused(
        const f16* __restrict__ xh, const f16* __restrict__ wih,
        const f16* __restrict__ whh, const float* __restrict__ biasc,
        const float* __restrict__ bhns, const float* __restrict__ h0,
        float* __restrict__ out, f16* __restrict__ yring, f16* __restrict__ ipring,
        int* flags) {
    __shared__ __align__(16) char smem[SMEM_BYTES];
    const int bid = blockIdx.x, tid = threadIdx.x;
    const int x = bid & 7, j = bid >> 3;
    const int lgrp = j / 5, role = j % 5;
    const int lg = lgrp * 8 + x;                // 0..23, same-XCD as its workers
    const int l = lg >> 2, g = lg & 3;
    if (role == 0) {
        scan_role(ipring, yring, whh, bhns, h0, out, flags, smem, l, g, tid);
    } else {
        const int q = role - 1;
        const float* bias = biasc + l * G3;
        f16* dstb = ipring + (long)lg * NRING * IPSLOT;
        if (l == 0) {
            worker_role<128>(xh, true, g, wih, bias, dstb, flags,
                             0, lg, 0, q, smem, tid);
        } else {
            int plg = (l - 1) * 4 + g;
            const f16* Wl = wih + 768 * 128 + (long)(l - 1) * G3 * HID;
            const f16* src = yring + (long)plg * NRING * 512 * HID;
            worker_role<256>(src, false, g, Wl, bias, dstb, flags,
                             l, lg, plg, q, smem, tid);
        }
    }
}

extern "C" void kernel_launch(void* const* d_in, const int* in_sizes, int n_in,
                              void* d_out, int out_size, void* d_ws, size_t ws_size,
                              hipStream_t stream) {
    const float* x     = (const float*)d_in[0];   // [2048,64,128]
    const float* h0    = (const float*)d_in[1];   // [6,64,256]
    const float* w_ih0 = (const float*)d_in[2];   // [768,128]
    const float* w_ihr = (const float*)d_in[3];   // [5,768,256]
    const float* w_hh  = (const float*)d_in[4];   // [6,768,256]
    const float* b_ih  = (const float*)d_in[5];   // [6,768]
    const float* b_hh  = (const float*)d_in[6];   // [6,768]
    float* out = (float*)d_out;                   // [6,64,256]

    char* p = (char*)d_ws;
    f16* xh      = (f16*)p;   p += (long)T_TOT * BATCH * 128 * 2;        // 33.5 MB
    f16* wih     = (f16*)p;   p += (long)(768 * 128 + 5 * 768 * 256) * 2;
    f16* whh     = (f16*)p;   p += (long)6 * 768 * 256 * 2;
    float* biasc = (float*)p; p += (long)6 * G3 * 4;
    float* bhns  = (float*)p; p += (long)6 * 256 * 4;
    f16* yring   = (f16*)p;   p += (long)20 * NRING * 512 * HID * 2;     // 21 MB
    f16* ipring  = (f16*)p;   p += (long)24 * NRING * IPSLOT * 2;        // 75.5 MB
    int* flags   = (int*)p;   p += 1024;

    hipMemsetAsync(flags, 0, 1024, stream);
    cvt_f16<<<16384, 256, 0, stream>>>(x, xh, T_TOT * BATCH * 128);
    cvt_f16<<<96, 256, 0, stream>>>(w_ih0, wih, 768 * 128);
    cvt_f16<<<960, 256, 0, stream>>>(w_ihr, wih + 768 * 128, 5 * 768 * 256);
    cvt_whh<<<1152, 256, 0, stream>>>(w_hh, whh, 6 * 768 * 256);
    bias_prep<<<18, 256, 0, stream>>>(b_ih, b_hh, biasc);
    bhn_prep<<<6, 256, 0, stream>>>(b_hh, bhns);

    gru_fused<<<120, 512, 0, stream>>>(xh, wih, whh, biasc, bhns, h0, out,
                                       yring, ipring, flags);
}